// Round 1
// baseline (180.300 us; speedup 1.0000x reference)
//
#include <hip/hip_runtime.h>

#define ALPHA 0.2f

typedef __attribute__((ext_vector_type(4))) short short4v;
typedef __attribute__((ext_vector_type(8))) short short8v;
typedef __attribute__((ext_vector_type(4))) float f32x4;

__device__ __forceinline__ short f2bf(float f) {
  union { float f; unsigned u; } v; v.f = f;
  unsigned r = v.u + 0x7fffu + ((v.u >> 16) & 1u);   // RNE to bf16
  return (short)(r >> 16);
}

// ------------------------------------------------------------------
// K1: h = x@W  -> hT (bf16, [64][8192]);  s1 = h@a1, s2 = h@a2 (fp32)
// grid 256 blocks x 256 thr; 32 rows/block; thread = (row = t>>3, fg = t&7)
// ------------------------------------------------------------------
__global__ __launch_bounds__(256) void k1_proj(
    const float* __restrict__ x, const float* __restrict__ W,
    const float* __restrict__ avec,
    short* __restrict__ hT, float* __restrict__ s1, float* __restrict__ s2) {
  __shared__ float xl[32 * 132];     // 32 rows x 128 k, stride 132 (pad, 16B-aligned)
  __shared__ float Wl[128 * 64];
  const int t   = threadIdx.x;
  const int rb  = blockIdx.x;
  const int row = t >> 3;
  const int fg  = t & 7;
  float acc[8];
#pragma unroll
  for (int e = 0; e < 8; e++) acc[e] = 0.f;

  for (int kc = 0; kc < 4; kc++) {
#pragma unroll
    for (int u = 0; u < 4; u++) {            // x chunk: 1024 float4
      int lin = t + u * 256;
      int r = lin >> 5, c4 = lin & 31;
      float4 v = *(const float4*)(x + (size_t)(rb * 32 + r) * 512 + kc * 128 + c4 * 4);
      *(float4*)(xl + r * 132 + c4 * 4) = v;
    }
#pragma unroll
    for (int u = 0; u < 8; u++) {            // W chunk: 2048 float4
      int lin = t + u * 256;
      int r = lin >> 4, c4 = lin & 15;
      float4 v = *(const float4*)(W + (size_t)(kc * 128 + r) * 64 + c4 * 4);
      *(float4*)(Wl + r * 64 + c4 * 4) = v;
    }
    __syncthreads();
#pragma unroll 8
    for (int k = 0; k < 128; k++) {
      float xv = xl[row * 132 + k];
      float4 w0 = *(const float4*)(Wl + k * 64 + fg * 8);
      float4 w1 = *(const float4*)(Wl + k * 64 + fg * 8 + 4);
      acc[0] = fmaf(xv, w0.x, acc[0]); acc[1] = fmaf(xv, w0.y, acc[1]);
      acc[2] = fmaf(xv, w0.z, acc[2]); acc[3] = fmaf(xv, w0.w, acc[3]);
      acc[4] = fmaf(xv, w1.x, acc[4]); acc[5] = fmaf(xv, w1.y, acc[5]);
      acc[6] = fmaf(xv, w1.z, acc[6]); acc[7] = fmaf(xv, w1.w, acc[7]);
    }
    __syncthreads();
  }

  // s1/s2: reduce over the 8 fg-lanes of this row (consecutive lanes, xor 1,2,4)
  float p1 = 0.f, p2 = 0.f;
#pragma unroll
  for (int e = 0; e < 8; e++) {
    p1 = fmaf(acc[e], avec[fg * 8 + e], p1);
    p2 = fmaf(acc[e], avec[64 + fg * 8 + e], p2);
  }
  p1 += __shfl_xor(p1, 1, 64); p1 += __shfl_xor(p1, 2, 64); p1 += __shfl_xor(p1, 4, 64);
  p2 += __shfl_xor(p2, 1, 64); p2 += __shfl_xor(p2, 2, 64); p2 += __shfl_xor(p2, 4, 64);
  const int gi = rb * 32 + row;
  if (fg == 0) { s1[gi] = p1; s2[gi] = p2; }
  // hT[f][i] bf16
#pragma unroll
  for (int e = 0; e < 8; e++)
    hT[(size_t)(fg * 8 + e) * 8192 + gi] = f2bf(acc[e]);
}

// ------------------------------------------------------------------
// K2: fused score-gen + softmax-weights + PV (MFMA), j-split by KS.
// block = 256 thr (4 waves); 64 rows/block; chunk = 64 j.
// num[ks][8192][64] (fp32 unnormalized), den[ks][8192].
// ------------------------------------------------------------------
__global__ __launch_bounds__(256) void k2_attn(
    const float* __restrict__ adj, const short* __restrict__ hT,
    const float* __restrict__ s1, const float* __restrict__ s2,
    float* __restrict__ num, float* __restrict__ den,
    const int KS, const int JSPAN) {
  __shared__ short At[64 * 68];      // weights tile, bf16, row stride 68 (pad)
  const int t    = threadIdx.x;
  const int wv   = t >> 6;
  const int lane = t & 63;
  const int lq   = lane >> 4;        // 0..3
  const int lr   = lane & 15;        // 0..15
  const int rb   = blockIdx.x & 127;
  const int ks   = blockIdx.x >> 7;
  const int r0   = rb << 6;
  const int j0   = ks * JSPAN;
  const int nchunk = JSPAN >> 6;

  int rowloc[4]; float s1v[4]; float denom_p[4];
  f32x4 acc[4];
#pragma unroll
  for (int rr = 0; rr < 4; rr++) {
    rowloc[rr] = wv * 16 + rr * 4 + lq;      // fixed across chunks
    s1v[rr] = s1[r0 + rowloc[rr]];
    denom_p[rr] = 0.f;
  }
#pragma unroll
  for (int fb = 0; fb < 4; fb++) acc[fb] = (f32x4){0.f, 0.f, 0.f, 0.f};

  // prologue prefetch (chunk 0)
  float4 adjv[4]; float4 s2v;
  s2v = *(const float4*)(s2 + j0 + lr * 4);
#pragma unroll
  for (int rr = 0; rr < 4; rr++)
    adjv[rr] = *(const float4*)(adj + (size_t)(r0 + rowloc[rr]) * 8192 + j0 + lr * 4);

  for (int c = 0; c < nchunk; c++) {
    const int jc = j0 + c * 64;
    // -------- Phase A: w = exp(leaky_relu(s1+s2)*adj); denom += w; At <- bf16(w)
#pragma unroll
    for (int rr = 0; rr < 4; rr++) {
      float z0 = s1v[rr] + s2v.x; z0 = fmaxf(z0, ALPHA * z0) * adjv[rr].x;
      float z1 = s1v[rr] + s2v.y; z1 = fmaxf(z1, ALPHA * z1) * adjv[rr].y;
      float z2 = s1v[rr] + s2v.z; z2 = fmaxf(z2, ALPHA * z2) * adjv[rr].z;
      float z3 = s1v[rr] + s2v.w; z3 = fmaxf(z3, ALPHA * z3) * adjv[rr].w;
      float w0 = __expf(z0), w1 = __expf(z1), w2 = __expf(z2), w3 = __expf(z3);
      denom_p[rr] += (w0 + w1) + (w2 + w3);
      short4v pk = { f2bf(w0), f2bf(w1), f2bf(w2), f2bf(w3) };
      *(short4v*)(At + rowloc[rr] * 68 + lr * 4) = pk;
    }
    __syncthreads();
    // -------- prefetch next chunk's adj/s2 (in flight across the MFMA phase)
    const int jn = (c + 1 < nchunk) ? jc + 64 : j0;
    float4 s2n = *(const float4*)(s2 + jn + lr * 4);
    float4 adjn[4];
#pragma unroll
    for (int rr = 0; rr < 4; rr++)
      adjn[rr] = *(const float4*)(adj + (size_t)(r0 + rowloc[rr]) * 8192 + jn + lr * 4);
    // -------- Phase B: 2 K-steps of 32, 4 f-blocks
#pragma unroll
    for (int kk = 0; kk < 2; kk++) {
      const int k0 = kk * 32;
      union { short4v h[2]; short8v v; } au;
      au.h[0] = *(const short4v*)(At + (wv * 16 + lr) * 68 + k0 + lq * 4);
      au.h[1] = *(const short4v*)(At + (wv * 16 + lr) * 68 + k0 + 16 + lq * 4);
#pragma unroll
      for (int fb = 0; fb < 4; fb++) {
        const short* bp = hT + (size_t)(fb * 16 + lr) * 8192 + jc + k0 + lq * 4;
        union { short4v h[2]; short8v v; } bu;
        bu.h[0] = *(const short4v*)(bp);
        bu.h[1] = *(const short4v*)(bp + 16);
        acc[fb] = __builtin_amdgcn_mfma_f32_16x16x32_bf16(au.v, bu.v, acc[fb], 0, 0, 0);
      }
    }
    __syncthreads();
    s2v = s2n;
#pragma unroll
    for (int rr = 0; rr < 4; rr++) adjv[rr] = adjn[rr];
  }

  // -------- epilogue: partial denominators and numerators
#pragma unroll
  for (int rr = 0; rr < 4; rr++) {
    float d = denom_p[rr];
    d += __shfl_xor(d, 1, 64); d += __shfl_xor(d, 2, 64);
    d += __shfl_xor(d, 4, 64); d += __shfl_xor(d, 8, 64);
    if (lr == 0) den[(size_t)ks * 8192 + r0 + rowloc[rr]] = d;
  }
  float* np = num + (size_t)ks * 524288;
#pragma unroll
  for (int fb = 0; fb < 4; fb++)
#pragma unroll
    for (int r = 0; r < 4; r++)
      np[(size_t)(r0 + wv * 16 + lq * 4 + r) * 64 + fb * 16 + lr] = acc[fb][r];
}

// ------------------------------------------------------------------
// K3: out = elu( sum_ks num / sum_ks den )
// ------------------------------------------------------------------
__global__ __launch_bounds__(256) void k3_norm(
    const float* __restrict__ num, const float* __restrict__ den,
    float* __restrict__ out, const int KS) {
  const int idx = blockIdx.x * 256 + threadIdx.x;   // 0..524287
  const int row = idx >> 6;
  float n = 0.f, d = 0.f;
  for (int ksi = 0; ksi < KS; ksi++) {
    n += num[(size_t)ksi * 524288 + idx];
    d += den[ksi * 8192 + row];
  }
  float v = n / d;
  out[idx] = v > 0.f ? v : (__expf(v) - 1.f);
}

extern "C" void kernel_launch(void* const* d_in, const int* in_sizes, int n_in,
                              void* d_out, int out_size, void* d_ws, size_t ws_size,
                              hipStream_t stream) {
  const float* x   = (const float*)d_in[0];
  const float* adj = (const float*)d_in[1];
  const float* W   = (const float*)d_in[2];
  const float* av  = (const float*)d_in[3];
  float* out = (float*)d_out;
  char* ws = (char*)d_ws;

  short* hT = (short*)ws;                                  // 64*8192*2 = 1 MB
  float* s1 = (float*)(ws + (1 << 20));                    // 32 KB
  float* s2 = (float*)(ws + (1 << 20) + 32768);            // 32 KB
  float* num = (float*)(ws + (1 << 20) + 65536);
  int KS = 4;
  while (KS > 1) {
    size_t need = (size_t)(1 << 20) + 65536 + (size_t)KS * (524288u * 4u + 32768u);
    if (need <= ws_size) break;
    KS >>= 1;
  }
  float* den = num + (size_t)KS * 524288;

  hipLaunchKernelGGL(k1_proj, dim3(256), dim3(256), 0, stream, x, W, av, hT, s1, s2);
  hipLaunchKernelGGL(k2_attn, dim3(128 * KS), dim3(256), 0, stream,
                     adj, hT, s1, s2, num, den, KS, 8192 / KS);
  hipLaunchKernelGGL(k3_norm, dim3(2048), dim3(256), 0, stream, num, den, out, KS);
}

// Round 2
// 170.057 us; speedup vs baseline: 1.0602x; 1.0602x over previous
//
#include <hip/hip_runtime.h>

#define ALPHA 0.2f

typedef __attribute__((ext_vector_type(4))) short short4v;
typedef __attribute__((ext_vector_type(8))) short short8v;
typedef __attribute__((ext_vector_type(4))) float f32x4;

__device__ __forceinline__ short f2bf(float f) {
  union { float f; unsigned u; } v; v.f = f;
  unsigned r = v.u + 0x7fffu + ((v.u >> 16) & 1u);   // RNE to bf16
  return (short)(r >> 16);
}

// ------------------------------------------------------------------
// K1: h = x@W  -> hT (bf16, [64][8192]);  s1 = h@a1, s2 = h@a2 (fp32)
// ------------------------------------------------------------------
__global__ __launch_bounds__(256) void k1_proj(
    const float* __restrict__ x, const float* __restrict__ W,
    const float* __restrict__ avec,
    short* __restrict__ hT, float* __restrict__ s1, float* __restrict__ s2) {
  __shared__ float xl[32 * 132];
  __shared__ float Wl[128 * 64];
  const int t   = threadIdx.x;
  const int rb  = blockIdx.x;
  const int row = t >> 3;
  const int fg  = t & 7;
  float acc[8];
#pragma unroll
  for (int e = 0; e < 8; e++) acc[e] = 0.f;

  for (int kc = 0; kc < 4; kc++) {
#pragma unroll
    for (int u = 0; u < 4; u++) {
      int lin = t + u * 256;
      int r = lin >> 5, c4 = lin & 31;
      float4 v = *(const float4*)(x + (size_t)(rb * 32 + r) * 512 + kc * 128 + c4 * 4);
      *(float4*)(xl + r * 132 + c4 * 4) = v;
    }
#pragma unroll
    for (int u = 0; u < 8; u++) {
      int lin = t + u * 256;
      int r = lin >> 4, c4 = lin & 15;
      float4 v = *(const float4*)(W + (size_t)(kc * 128 + r) * 64 + c4 * 4);
      *(float4*)(Wl + r * 64 + c4 * 4) = v;
    }
    __syncthreads();
#pragma unroll 8
    for (int k = 0; k < 128; k++) {
      float xv = xl[row * 132 + k];
      float4 w0 = *(const float4*)(Wl + k * 64 + fg * 8);
      float4 w1 = *(const float4*)(Wl + k * 64 + fg * 8 + 4);
      acc[0] = fmaf(xv, w0.x, acc[0]); acc[1] = fmaf(xv, w0.y, acc[1]);
      acc[2] = fmaf(xv, w0.z, acc[2]); acc[3] = fmaf(xv, w0.w, acc[3]);
      acc[4] = fmaf(xv, w1.x, acc[4]); acc[5] = fmaf(xv, w1.y, acc[5]);
      acc[6] = fmaf(xv, w1.z, acc[6]); acc[7] = fmaf(xv, w1.w, acc[7]);
    }
    __syncthreads();
  }

  float p1 = 0.f, p2 = 0.f;
#pragma unroll
  for (int e = 0; e < 8; e++) {
    p1 = fmaf(acc[e], avec[fg * 8 + e], p1);
    p2 = fmaf(acc[e], avec[64 + fg * 8 + e], p2);
  }
  p1 += __shfl_xor(p1, 1, 64); p1 += __shfl_xor(p1, 2, 64); p1 += __shfl_xor(p1, 4, 64);
  p2 += __shfl_xor(p2, 1, 64); p2 += __shfl_xor(p2, 2, 64); p2 += __shfl_xor(p2, 4, 64);
  const int gi = rb * 32 + row;
  if (fg == 0) { s1[gi] = p1; s2[gi] = p2; }
#pragma unroll
  for (int e = 0; e < 8; e++)
    hT[(size_t)(fg * 8 + e) * 8192 + gi] = f2bf(acc[e]);
}

// ------------------------------------------------------------------
// K2: fused score-gen + softmax-weights + PV (MFMA), j-split by KS.
// NO barriers: each wave's LDS tile is private (writes rows wv*16+rr*4+lq,
// reads rows wv*16+lr). Depth-2 register prefetch of adj (ping/pong named
// buffers; no runtime-indexed arrays).
// ------------------------------------------------------------------
__global__ __launch_bounds__(256, 4) void k2_attn(
    const float* __restrict__ adj, const short* __restrict__ hT,
    const float* __restrict__ s1, const float* __restrict__ s2,
    float* __restrict__ num, float* __restrict__ den,
    const int KS, const int JSPAN) {
  __shared__ short At[64 * 68];
  const int t    = threadIdx.x;
  const int wvi  = t >> 6;
  const int lane = t & 63;
  const int lq   = lane >> 4;        // 0..3
  const int lr   = lane & 15;        // 0..15
  const int rb   = blockIdx.x & 127;
  const int ks   = blockIdx.x >> 7;
  const int r0   = rb << 6;
  const int j0   = ks * JSPAN;
  const int nchunk = JSPAN >> 6;     // 128/KS >= 16, even

  short* Aw = At + (wvi * 16) * 68;  // wave-private 16x64 tile

  int rowloc[4]; float s1v[4]; float denom_p[4];
  f32x4 acc[4];
#pragma unroll
  for (int rr = 0; rr < 4; rr++) {
    rowloc[rr] = wvi * 16 + rr * 4 + lq;
    s1v[rr] = s1[r0 + rowloc[rr]];
    denom_p[rr] = 0.f;
  }
#pragma unroll
  for (int fb = 0; fb < 4; fb++) acc[fb] = (f32x4){0.f, 0.f, 0.f, 0.f};

  float4 aA[4], aB[4]; float4 s2A, s2B;
  {
    s2A = *(const float4*)(s2 + j0 + lr * 4);
    s2B = *(const float4*)(s2 + j0 + 64 + lr * 4);
#pragma unroll
    for (int rr = 0; rr < 4; rr++) {
      const float* ap = adj + (size_t)(r0 + rowloc[rr]) * 8192 + j0 + lr * 4;
      aA[rr] = *(const float4*)(ap);
      aB[rr] = *(const float4*)(ap + 64);
    }
  }

#define K2_BODY(CUR, S2C, CIDX) do {                                          \
    const int jc__ = j0 + (CIDX) * 64;                                        \
    float w__[4][4];                                                          \
    _Pragma("unroll")                                                         \
    for (int rr = 0; rr < 4; rr++) {                                          \
      float z0 = s1v[rr] + S2C.x; z0 = fmaxf(z0, ALPHA * z0) * CUR[rr].x;     \
      float z1 = s1v[rr] + S2C.y; z1 = fmaxf(z1, ALPHA * z1) * CUR[rr].y;     \
      float z2 = s1v[rr] + S2C.z; z2 = fmaxf(z2, ALPHA * z2) * CUR[rr].z;     \
      float z3 = s1v[rr] + S2C.w; z3 = fmaxf(z3, ALPHA * z3) * CUR[rr].w;     \
      w__[rr][0] = __expf(z0); w__[rr][1] = __expf(z1);                       \
      w__[rr][2] = __expf(z2); w__[rr][3] = __expf(z3);                       \
    }                                                                         \
    {                                                                         \
      const int cp__ = (CIDX) + 2;                                            \
      const int jn__ = j0 + ((cp__ < nchunk) ? cp__ : 0) * 64;                \
      S2C = *(const float4*)(s2 + jn__ + lr * 4);                             \
      _Pragma("unroll")                                                       \
      for (int rr = 0; rr < 4; rr++)                                          \
        CUR[rr] = *(const float4*)(adj + (size_t)(r0 + rowloc[rr]) * 8192 +   \
                                   jn__ + lr * 4);                            \
    }                                                                         \
    _Pragma("unroll")                                                         \
    for (int rr = 0; rr < 4; rr++) {                                          \
      denom_p[rr] += (w__[rr][0] + w__[rr][1]) + (w__[rr][2] + w__[rr][3]);   \
      short4v pk = { f2bf(w__[rr][0]), f2bf(w__[rr][1]),                      \
                     f2bf(w__[rr][2]), f2bf(w__[rr][3]) };                    \
      *(short4v*)(Aw + (rr * 4 + lq) * 68 + lr * 4) = pk;                     \
    }                                                                         \
    _Pragma("unroll")                                                         \
    for (int kk = 0; kk < 2; kk++) {                                          \
      const int k0 = kk * 32;                                                 \
      union { short4v h[2]; short8v v; } au, bu;                              \
      au.h[0] = *(const short4v*)(Aw + lr * 68 + k0 + lq * 4);                \
      au.h[1] = *(const short4v*)(Aw + lr * 68 + k0 + 16 + lq * 4);           \
      _Pragma("unroll")                                                       \
      for (int fb = 0; fb < 4; fb++) {                                        \
        const short* bp = hT + (size_t)(fb * 16 + lr) * 8192 + jc__ + k0 +    \
                          lq * 4;                                             \
        bu.h[0] = *(const short4v*)(bp);                                      \
        bu.h[1] = *(const short4v*)(bp + 16);                                 \
        acc[fb] = __builtin_amdgcn_mfma_f32_16x16x32_bf16(au.v, bu.v,         \
                                                          acc[fb], 0, 0, 0); \
      }                                                                       \
    }                                                                         \
  } while (0)

  for (int c = 0; c < nchunk; c += 2) {
    K2_BODY(aA, s2A, c);
    K2_BODY(aB, s2B, c + 1);
  }
#undef K2_BODY

  // epilogue: partial denominators and numerators
#pragma unroll
  for (int rr = 0; rr < 4; rr++) {
    float d = denom_p[rr];
    d += __shfl_xor(d, 1, 64); d += __shfl_xor(d, 2, 64);
    d += __shfl_xor(d, 4, 64); d += __shfl_xor(d, 8, 64);
    if (lr == 0) den[(size_t)ks * 8192 + r0 + rowloc[rr]] = d;
  }
  float* np = num + (size_t)ks * 524288;
#pragma unroll
  for (int fb = 0; fb < 4; fb++)
#pragma unroll
    for (int r = 0; r < 4; r++)
      np[(size_t)(r0 + wvi * 16 + lq * 4 + r) * 64 + fb * 16 + lr] = acc[fb][r];
}

// ------------------------------------------------------------------
// K3: out = elu( sum_ks num / sum_ks den )
// ------------------------------------------------------------------
__global__ __launch_bounds__(256) void k3_norm(
    const float* __restrict__ num, const float* __restrict__ den,
    float* __restrict__ out, const int KS) {
  const int idx = blockIdx.x * 256 + threadIdx.x;   // 0..524287
  const int row = idx >> 6;
  float n = 0.f, d = 0.f;
  for (int ksi = 0; ksi < KS; ksi++) {
    n += num[(size_t)ksi * 524288 + idx];
    d += den[ksi * 8192 + row];
  }
  float v = n / d;
  out[idx] = v > 0.f ? v : (__expf(v) - 1.f);
}

extern "C" void kernel_launch(void* const* d_in, const int* in_sizes, int n_in,
                              void* d_out, int out_size, void* d_ws, size_t ws_size,
                              hipStream_t stream) {
  const float* x   = (const float*)d_in[0];
  const float* adj = (const float*)d_in[1];
  const float* W   = (const float*)d_in[2];
  const float* av  = (const float*)d_in[3];
  float* out = (float*)d_out;
  char* ws = (char*)d_ws;

  short* hT = (short*)ws;                                  // 1 MB
  float* s1 = (float*)(ws + (1 << 20));                    // 32 KB
  float* s2 = (float*)(ws + (1 << 20) + 32768);            // 32 KB
  float* num = (float*)(ws + (1 << 20) + 65536);
  int KS = 8;
  while (KS > 1) {
    size_t need = (size_t)(1 << 20) + 65536 + (size_t)KS * (524288u * 4u + 32768u);
    if (need <= ws_size) break;
    KS >>= 1;
  }
  float* den = num + (size_t)KS * 524288;

  hipLaunchKernelGGL(k1_proj, dim3(256), dim3(256), 0, stream, x, W, av, hT, s1, s2);
  hipLaunchKernelGGL(k2_attn, dim3(128 * KS), dim3(256), 0, stream,
                     adj, hT, s1, s2, num, den, KS, 8192 / KS);
  hipLaunchKernelGGL(k3_norm, dim3(2048), dim3(256), 0, stream, num, den, out, KS);
}